// Round 1
// baseline (1983.539 us; speedup 1.0000x reference)
//
#include <hip/hip_runtime.h>
#include <stdint.h>

using f32x4  = __attribute__((ext_vector_type(4))) float;
using bf16x8 = __attribute__((ext_vector_type(8))) short;

#define NB  16
#define NC  256
#define NC2 128
#define NN  4096

__device__ __forceinline__ unsigned short f2bf(float v) {
    unsigned int u = __float_as_uint(v);
    u = u + 0x7fffu + ((u >> 16) & 1u);
    return (unsigned short)(u >> 16);
}
__device__ __forceinline__ float bf2f(unsigned short h) {
    return __uint_as_float(((unsigned int)h) << 16);
}

// ---------------------------------------------------------------------------
// Phase 1: 1x1-conv projections (f32 SGEMM), write Q/K as bf16 hi/lo pairs
// [b][n][o] and V as bf16 [b][o][n].
// Grid: 16 b x 64 ntiles x 4 units (Q, K, V-lo-half, V-hi-half) = 4096 blocks.
// ---------------------------------------------------------------------------
__global__ __launch_bounds__(256, 4) void qkv_kernel(
    const float* __restrict__ x, const float* __restrict__ y,
    const float* __restrict__ Wq, const float* __restrict__ bq,
    const float* __restrict__ Wk, const float* __restrict__ bk,
    const float* __restrict__ Wv, const float* __restrict__ bv,
    unsigned short* __restrict__ Qhi, unsigned short* __restrict__ Qlo,
    unsigned short* __restrict__ Khi, unsigned short* __restrict__ Klo,
    unsigned short* __restrict__ Vo)
{
    __shared__ float Sld[8][64];    // src tile: 8 channels x 64 positions
    __shared__ float Wld[8][128];   // weight tile: 8 channels x 128 outputs

    const int bid   = blockIdx.x;
    const int unit  = bid & 3;
    const int ntile = (bid >> 2) & 63;
    const int bb    = bid >> 8;
    const int n0    = ntile * 64;

    const float* src  = (unit == 0) ? x : y;
    const float* W    = (unit == 0) ? Wq : ((unit == 1) ? Wk : Wv);
    const float* bias = (unit == 0) ? bq : ((unit == 1) ? bk : bv);
    const int o0 = (unit == 3) ? 128 : 0;

    const int t  = threadIdx.x;
    const int tn = t & 15;   // 4 positions each
    const int to = t >> 4;   // 8 outputs each

    float acc[4][8];
    #pragma unroll
    for (int i = 0; i < 4; ++i)
        #pragma unroll
        for (int j = 0; j < 8; ++j) acc[i][j] = 0.f;

    float bs[8];
    #pragma unroll
    for (int j = 0; j < 8; ++j) bs[j] = bias[o0 + to*8 + j];

    #pragma unroll 1
    for (int step = 0; step < 32; ++step) {
        const int c0 = step * 8;
        // prefetch into registers (no LDS touch before barrier)
        f32x4 sv;
        if (t < 128)
            sv = *(const f32x4*)(src + ((size_t)(bb*NC + c0 + (t>>4)))*NN + n0 + (t&15)*4);
        f32x4 wv4 = *(const f32x4*)(W + (size_t)(o0 + (t>>1))*NC + c0 + (t&1)*4);
        __syncthreads();   // previous step's compute done reading LDS
        if (t < 128)
            *(f32x4*)&Sld[t>>4][(t&15)*4] = sv;
        {
            const int r = t >> 1, cc = (t & 1) * 4;
            Wld[cc+0][r] = wv4[0]; Wld[cc+1][r] = wv4[1];
            Wld[cc+2][r] = wv4[2]; Wld[cc+3][r] = wv4[3];
        }
        __syncthreads();
        #pragma unroll
        for (int c = 0; c < 8; ++c) {
            f32x4 av = *(const f32x4*)&Sld[c][tn*4];
            f32x4 b0 = *(const f32x4*)&Wld[c][to*8];
            f32x4 b1 = *(const f32x4*)&Wld[c][to*8+4];
            #pragma unroll
            for (int i = 0; i < 4; ++i) {
                const float a = av[i];
                acc[i][0] = fmaf(a, b0[0], acc[i][0]);
                acc[i][1] = fmaf(a, b0[1], acc[i][1]);
                acc[i][2] = fmaf(a, b0[2], acc[i][2]);
                acc[i][3] = fmaf(a, b0[3], acc[i][3]);
                acc[i][4] = fmaf(a, b1[0], acc[i][4]);
                acc[i][5] = fmaf(a, b1[1], acc[i][5]);
                acc[i][6] = fmaf(a, b1[2], acc[i][6]);
                acc[i][7] = fmaf(a, b1[3], acc[i][7]);
            }
        }
    }

    if (unit < 2) {
        unsigned short* dh = (unit == 0) ? Qhi : Khi;
        unsigned short* dl = (unit == 0) ? Qlo : Klo;
        #pragma unroll
        for (int i = 0; i < 4; ++i) {
            const int n = n0 + tn*4 + i;
            union { unsigned short u16[8]; uint4 u4; } hh, ll;
            #pragma unroll
            for (int j = 0; j < 8; ++j) {
                const float v = acc[i][j] + bs[j];
                const unsigned short h = f2bf(v);
                hh.u16[j] = h;
                ll.u16[j] = f2bf(v - bf2f(h));
            }
            const size_t off = ((size_t)bb*NN + n)*NC2 + to*8;
            *(uint4*)(dh + off) = hh.u4;
            *(uint4*)(dl + off) = ll.u4;
        }
    } else {
        #pragma unroll
        for (int j = 0; j < 8; ++j) {
            const int o = o0 + to*8 + j;
            union { unsigned short u16[4]; uint2 u2; } pk;
            #pragma unroll
            for (int i = 0; i < 4; ++i) pk.u16[i] = f2bf(acc[i][j] + bs[j]);
            const size_t off = ((size_t)bb*NC + o)*NN + n0 + tn*4;
            *(uint2*)(Vo + off) = pk.u2;
        }
    }
}

// ---------------------------------------------------------------------------
// Phase 2: flash attention + fused gamma*out + y epilogue.
// Block: 256 threads (4 waves x 16 query rows = BM 64). BN = 64 keys/iter.
// Energy = qh*kh + ql*kh + qh*kl (hi/lo split -> f32-accurate logits).
// LDS tiles XOR-swizzled (16B granule) to kill the [*][128]-bf16 row conflict.
// ---------------------------------------------------------------------------
__global__ __launch_bounds__(256, 2) void attn_kernel(
    const unsigned short* __restrict__ Qhi, const unsigned short* __restrict__ Qlo,
    const unsigned short* __restrict__ Khi, const unsigned short* __restrict__ Klo,
    const unsigned short* __restrict__ Vo,
    const float* __restrict__ yg, const float* __restrict__ gamma,
    float* __restrict__ outp)
{
    __shared__ short khi[64*128];   // 16 KB, rows n (256B), swizzled
    __shared__ short klo[64*128];   // 16 KB
    __shared__ short vld[256*64];   // 32 KB, rows o (128B), swizzled
    __shared__ short pld[4*16*64];  // 8 KB, per-wave 16x64 P tile, swizzled

    const int bb = blockIdx.x >> 6;
    const int m0 = (blockIdx.x & 63) * 64;
    const int t  = threadIdx.x;
    const int cl = t & 15;
    const int gp = (t >> 4) & 3;
    const int wv = t >> 6;

    // Q fragments (A operand): row = lane&15, k = kk*32 + gp*8 + j
    bf16x8 qh[4], ql[4];
    {
        const int mrow = m0 + wv*16 + cl;
        const bf16x8* ph = (const bf16x8*)(Qhi + ((size_t)bb*NN + mrow)*NC2);
        const bf16x8* pl = (const bf16x8*)(Qlo + ((size_t)bb*NN + mrow)*NC2);
        #pragma unroll
        for (int kk = 0; kk < 4; ++kk) { qh[kk] = ph[kk*4+gp]; ql[kk] = pl[kk*4+gp]; }
    }

    f32x4 acc[16];
    #pragma unroll
    for (int i = 0; i < 16; ++i) acc[i] = (f32x4){0.f, 0.f, 0.f, 0.f};
    float m_run[4] = {-3.0e38f, -3.0e38f, -3.0e38f, -3.0e38f};
    float l_run[4] = {0.f, 0.f, 0.f, 0.f};

    const uint4* KhiG = (const uint4*)Khi + (size_t)bb*NN*16;  // 16 uint4 / row
    const uint4* KloG = (const uint4*)Klo + (size_t)bb*NN*16;
    const uint4* VG   = (const uint4*)Vo  + (size_t)bb*NC*512; // 512 uint4 / row

    #pragma unroll 1
    for (int it = 0; it < 64; ++it) {
        const int n0 = it * 64;
        // --- stage loads issued early (T14-style), LDS writes after barrier ---
        uint4 rk[8], rv[8];
        #pragma unroll
        for (int i = 0; i < 4; ++i) {
            const int slot = i*256 + t;
            const int n = slot >> 4, c16 = slot & 15;
            rk[i]   = KhiG[(size_t)(n0+n)*16 + c16];
            rk[i+4] = KloG[(size_t)(n0+n)*16 + c16];
        }
        #pragma unroll
        for (int i = 0; i < 8; ++i) {
            const int slot = i*256 + t;
            const int o = slot >> 3, c8 = slot & 7;
            rv[i] = VG[(size_t)o*512 + (n0>>3) + c8];
        }
        __syncthreads();   // all waves done reading previous tile
        #pragma unroll
        for (int i = 0; i < 4; ++i) {
            const int slot = i*256 + t;
            const int n = slot >> 4, c16 = slot & 15;
            const int dst = n*256 + (((c16<<4)) ^ ((n&7)<<4));
            *(uint4*)((char*)khi + dst) = rk[i];
            *(uint4*)((char*)klo + dst) = rk[i+4];
        }
        #pragma unroll
        for (int i = 0; i < 8; ++i) {
            const int slot = i*256 + t;
            const int o = slot >> 3, c8 = slot & 7;
            const int dst = o*128 + (((c8<<4)) ^ ((o&7)<<4));
            *(uint4*)((char*)vld + dst) = rv[i];
        }
        __syncthreads();   // tile visible

        // --- energy: E[m][n] over this wave's 16 rows x 64 keys ---
        f32x4 e[4];
        #pragma unroll
        for (int s = 0; s < 4; ++s) {
            f32x4 ac = {0.f, 0.f, 0.f, 0.f};
            const int n  = s*16 + cl;
            const int rb = n*256;
            const int sw = (n&7) << 4;
            #pragma unroll
            for (int kk = 0; kk < 4; ++kk) {
                const int ob = (kk*64 + gp*16) ^ sw;
                bf16x8 kh = *(const bf16x8*)((const char*)khi + rb + ob);
                bf16x8 kl = *(const bf16x8*)((const char*)klo + rb + ob);
                ac = __builtin_amdgcn_mfma_f32_16x16x32_bf16(qh[kk], kh, ac, 0, 0, 0);
                ac = __builtin_amdgcn_mfma_f32_16x16x32_bf16(ql[kk], kh, ac, 0, 0, 0);
                ac = __builtin_amdgcn_mfma_f32_16x16x32_bf16(qh[kk], kl, ac, 0, 0, 0);
            }
            e[s] = ac;
        }

        // --- online softmax; row r lives at (gp*4 + r), spread over 16 lanes ---
        float sc[4];
        #pragma unroll
        for (int r = 0; r < 4; ++r) {
            float mx = fmaxf(fmaxf(e[0][r], e[1][r]), fmaxf(e[2][r], e[3][r]));
            #pragma unroll
            for (int mk = 1; mk <= 8; mk <<= 1) mx = fmaxf(mx, __shfl_xor(mx, mk));
            const float mn = fmaxf(m_run[r], mx);
            const float s_ = __expf(m_run[r] - mn);
            m_run[r] = mn; sc[r] = s_;
            float rs = 0.f;
            #pragma unroll
            for (int s2 = 0; s2 < 4; ++s2) {
                const float p = __expf(e[s2][r] - mn);
                e[s2][r] = p;
                rs += p;
            }
            #pragma unroll
            for (int mk = 1; mk <= 8; mk <<= 1) rs += __shfl_xor(rs, mk);
            l_run[r] = l_run[r]*s_ + rs;
        }
        #pragma unroll
        for (int tt = 0; tt < 16; ++tt) {
            acc[tt][0] *= sc[0]; acc[tt][1] *= sc[1];
            acc[tt][2] *= sc[2]; acc[tt][3] *= sc[3];
        }

        // --- P -> LDS (bf16, swizzled), per-wave private region ---
        char* pb = (char*)pld + wv*2048;
        #pragma unroll
        for (int s2 = 0; s2 < 4; ++s2) {
            #pragma unroll
            for (int r = 0; r < 4; ++r) {
                const int row = gp*4 + r;
                const int nb  = (s2*16 + cl) * 2;
                *(short*)(pb + row*128 + (nb ^ ((row&7)<<4))) = (short)f2bf(e[s2][r]);
            }
        }

        // --- PV: acc[m][o] += P[m][n] * V[o][n] ---
        #pragma unroll
        for (int ks = 0; ks < 2; ++ks) {
            const int ob = ks*64 + gp*16;
            bf16x8 pa = *(const bf16x8*)(pb + cl*128 + (ob ^ ((cl&7)<<4)));
            #pragma unroll
            for (int tt = 0; tt < 16; ++tt) {
                const int o = tt*16 + cl;
                bf16x8 vf = *(const bf16x8*)((const char*)vld + o*128 + (ob ^ ((o&7)<<4)));
                acc[tt] = __builtin_amdgcn_mfma_f32_16x16x32_bf16(pa, vf, acc[tt], 0, 0, 0);
            }
        }
        // (next iteration's first __syncthreads orders PV reads vs. restaging)
    }

    // --- epilogue: out = gamma * acc/l + y ---
    float inv[4];
    #pragma unroll
    for (int r = 0; r < 4; ++r) inv[r] = 1.0f / l_run[r];
    const float ga = gamma[0];
    const int mbase = m0 + wv*16 + gp*4;
    #pragma unroll
    for (int tt = 0; tt < 16; ++tt) {
        const int o = tt*16 + cl;
        const size_t base = ((size_t)(bb*NC + o))*NN + mbase;
        f32x4 yv = *(const f32x4*)(yg + base);
        f32x4 ov;
        ov[0] = fmaf(acc[tt][0]*inv[0], ga, yv[0]);
        ov[1] = fmaf(acc[tt][1]*inv[1], ga, yv[1]);
        ov[2] = fmaf(acc[tt][2]*inv[2], ga, yv[2]);
        ov[3] = fmaf(acc[tt][3]*inv[3], ga, yv[3]);
        *(f32x4*)(outp + base) = ov;
    }
}

extern "C" void kernel_launch(void* const* d_in, const int* in_sizes, int n_in,
                              void* d_out, int out_size, void* d_ws, size_t ws_size,
                              hipStream_t stream) {
    (void)in_sizes; (void)n_in; (void)out_size; (void)ws_size;
    const float* x     = (const float*)d_in[0];
    const float* y     = (const float*)d_in[1];
    const float* Wq    = (const float*)d_in[2];
    const float* bq    = (const float*)d_in[3];
    const float* Wk    = (const float*)d_in[4];
    const float* bk    = (const float*)d_in[5];
    const float* Wv    = (const float*)d_in[6];
    const float* bv    = (const float*)d_in[7];
    const float* gamma = (const float*)d_in[8];
    float* out = (float*)d_out;

    unsigned short* Qhi = (unsigned short*)d_ws;
    unsigned short* Qlo = Qhi + (size_t)NB*NN*NC2;
    unsigned short* Khi = Qlo + (size_t)NB*NN*NC2;
    unsigned short* Klo = Khi + (size_t)NB*NN*NC2;
    unsigned short* Vo  = Klo + (size_t)NB*NN*NC2;  // 16*256*4096 bf16

    qkv_kernel<<<dim3(4096), dim3(256), 0, stream>>>(
        x, y, Wq, bq, Wk, bk, Wv, bv, Qhi, Qlo, Khi, Klo, Vo);
    attn_kernel<<<dim3(1024), dim3(256), 0, stream>>>(
        Qhi, Qlo, Khi, Klo, Vo, y, gamma, out);
}

// Round 2
// 720.634 us; speedup vs baseline: 2.7525x; 2.7525x over previous
//
#include <hip/hip_runtime.h>
#include <stdint.h>

using f32x4  = __attribute__((ext_vector_type(4))) float;
using bf16x8 = __attribute__((ext_vector_type(8))) short;

#define NB  16
#define NC  256
#define NC2 128
#define NN  4096

__device__ __forceinline__ unsigned short f2bf(float v) {
    unsigned int u = __float_as_uint(v);
    u = u + 0x7fffu + ((u >> 16) & 1u);
    return (unsigned short)(u >> 16);
}
__device__ __forceinline__ float bf2f(unsigned short h) {
    return __uint_as_float(((unsigned int)h) << 16);
}

__device__ __forceinline__ void gload16(const void* g, void* l) {
    __builtin_amdgcn_global_load_lds(
        (const __attribute__((address_space(1))) unsigned int*)g,
        (__attribute__((address_space(3))) unsigned int*)l, 16, 0, 0);
}

// ---------------------------------------------------------------------------
// Phase 1: 1x1-conv projections (f32 SGEMM).
//  - Q -> linear [b][n][128] bf16 hi/lo pairs (read straight to registers).
//  - K,V -> tile-major PRE-SWIZZLED workspace: per (b, 64-key tile) one 64 KB
//    block [khi 16K | klo 16K | V 32K] laid out exactly as attn's LDS image
//    (XOR-16B bank swizzle already applied), so attn can stage it with
//    linear global_load_lds.
// Grid: 16 b x 64 ntiles x 4 units (Q, K, V-lo, V-hi) = 4096 blocks.
// ---------------------------------------------------------------------------
__global__ __launch_bounds__(256, 4) void qkv_kernel(
    const float* __restrict__ x, const float* __restrict__ y,
    const float* __restrict__ Wq, const float* __restrict__ bq,
    const float* __restrict__ Wk, const float* __restrict__ bk,
    const float* __restrict__ Wv, const float* __restrict__ bv,
    unsigned short* __restrict__ Qhi, unsigned short* __restrict__ Qlo,
    char* __restrict__ KV)
{
    __shared__ float Sld[8][64];    // src tile: 8 channels x 64 positions
    __shared__ float Wld[8][128];   // weight tile: 8 channels x 128 outputs

    const int bid   = blockIdx.x;
    const int unit  = bid & 3;
    const int ntile = (bid >> 2) & 63;
    const int bb    = bid >> 8;
    const int n0    = ntile * 64;

    const float* src  = (unit == 0) ? x : y;
    const float* W    = (unit == 0) ? Wq : ((unit == 1) ? Wk : Wv);
    const float* bias = (unit == 0) ? bq : ((unit == 1) ? bk : bv);
    const int o0 = (unit == 3) ? 128 : 0;

    const int t  = threadIdx.x;
    const int tn = t & 15;   // 4 positions each
    const int to = t >> 4;   // 8 outputs each

    float acc[4][8];
    #pragma unroll
    for (int i = 0; i < 4; ++i)
        #pragma unroll
        for (int j = 0; j < 8; ++j) acc[i][j] = 0.f;

    float bs[8];
    #pragma unroll
    for (int j = 0; j < 8; ++j) bs[j] = bias[o0 + to*8 + j];

    #pragma unroll 1
    for (int step = 0; step < 32; ++step) {
        const int c0 = step * 8;
        f32x4 sv;
        if (t < 128)
            sv = *(const f32x4*)(src + ((size_t)(bb*NC + c0 + (t>>4)))*NN + n0 + (t&15)*4);
        f32x4 wv4 = *(const f32x4*)(W + (size_t)(o0 + (t>>1))*NC + c0 + (t&1)*4);
        __syncthreads();
        if (t < 128)
            *(f32x4*)&Sld[t>>4][(t&15)*4] = sv;
        {
            const int r = t >> 1, cc = (t & 1) * 4;
            Wld[cc+0][r] = wv4[0]; Wld[cc+1][r] = wv4[1];
            Wld[cc+2][r] = wv4[2]; Wld[cc+3][r] = wv4[3];
        }
        __syncthreads();
        #pragma unroll
        for (int c = 0; c < 8; ++c) {
            f32x4 av = *(const f32x4*)&Sld[c][tn*4];
            f32x4 b0 = *(const f32x4*)&Wld[c][to*8];
            f32x4 b1 = *(const f32x4*)&Wld[c][to*8+4];
            #pragma unroll
            for (int i = 0; i < 4; ++i) {
                const float a = av[i];
                acc[i][0] = fmaf(a, b0[0], acc[i][0]);
                acc[i][1] = fmaf(a, b0[1], acc[i][1]);
                acc[i][2] = fmaf(a, b0[2], acc[i][2]);
                acc[i][3] = fmaf(a, b0[3], acc[i][3]);
                acc[i][4] = fmaf(a, b1[0], acc[i][4]);
                acc[i][5] = fmaf(a, b1[1], acc[i][5]);
                acc[i][6] = fmaf(a, b1[2], acc[i][6]);
                acc[i][7] = fmaf(a, b1[3], acc[i][7]);
            }
        }
    }

    if (unit == 0) {
        // Q: linear hi/lo
        #pragma unroll
        for (int i = 0; i < 4; ++i) {
            const int n = n0 + tn*4 + i;
            union { unsigned short u16[8]; uint4 u4; } hh, ll;
            #pragma unroll
            for (int j = 0; j < 8; ++j) {
                const float v = acc[i][j] + bs[j];
                const unsigned short h = f2bf(v);
                hh.u16[j] = h;
                ll.u16[j] = f2bf(v - bf2f(h));
            }
            const size_t off = ((size_t)bb*NN + n)*NC2 + to*8;
            *(uint4*)(Qhi + off) = hh.u4;
            *(uint4*)(Qlo + off) = ll.u4;
        }
    } else if (unit == 1) {
        // K: pre-swizzled LDS image, hi at +0, lo at +16K
        char* kvt = KV + (((size_t)bb*64 + ntile) << 16);
        #pragma unroll
        for (int i = 0; i < 4; ++i) {
            const int nr = tn*4 + i;
            union { unsigned short u16[8]; uint4 u4; } hh, ll;
            #pragma unroll
            for (int j = 0; j < 8; ++j) {
                const float v = acc[i][j] + bs[j];
                const unsigned short h = f2bf(v);
                hh.u16[j] = h;
                ll.u16[j] = f2bf(v - bf2f(h));
            }
            const int dst = nr*256 + ((to<<4) ^ ((nr&7)<<4));
            *(uint4*)(kvt + dst)         = hh.u4;
            *(uint4*)(kvt + 16384 + dst) = ll.u4;
        }
    } else {
        // V: pre-swizzled LDS image at +32K, rows o (128B), 16B-granule XOR
        char* kvt = KV + (((size_t)bb*64 + ntile) << 16) + 32768;
        #pragma unroll
        for (int j = 0; j < 8; ++j) {
            const int o = o0 + to*8 + j;
            union { unsigned short u16[4]; uint2 u2; } pk;
            #pragma unroll
            for (int i = 0; i < 4; ++i) pk.u16[i] = f2bf(acc[i][j] + bs[j]);
            const int dst = o*128 + (((tn>>1)<<4) ^ ((o&7)<<4)) + (tn&1)*8;
            *(uint2*)(kvt + dst) = pk.u2;
        }
    }
}

// ---------------------------------------------------------------------------
// Phase 2: flash attention + fused gamma*out + y epilogue.
// 256 threads (4 waves x 16 query rows = BM 64). BN = 64 keys/iter.
// K/V staged with global_load_lds (linear dest; swizzle pre-applied by
// producer). Single 64 KB buffer; next tile's loads issued after the
// post-compute barrier; __syncthreads at loop top drains vmcnt.
// XCD-aware block swizzle: 128 consecutive logical blocks (2 batches) / XCD.
// ---------------------------------------------------------------------------
__global__ __launch_bounds__(256, 2) void attn_kernel(
    const unsigned short* __restrict__ Qhi, const unsigned short* __restrict__ Qlo,
    const char* __restrict__ KV,
    const float* __restrict__ yg, const float* __restrict__ gamma,
    float* __restrict__ outp)
{
    __shared__ __align__(16) char tile[65536]; // [khi 16K | klo 16K | V 32K]
    __shared__ __align__(16) short pld[4096];  // 8 KB, per-wave 16x64 P tile

    // T1: bijective XCD swizzle (1024 blocks, 1024%8==0)
    const int bid = ((blockIdx.x & 7) << 7) + (blockIdx.x >> 3);
    const int bb = bid >> 6;
    const int m0 = (bid & 63) * 64;
    const int t  = threadIdx.x;
    const int cl = t & 15;
    const int gp = (t >> 4) & 3;
    const int wv = t >> 6;

    // Q fragments (A operand): row = lane&15, k = kk*32 + gp*8 + j
    bf16x8 qh[4], ql[4];
    {
        const int mrow = m0 + wv*16 + cl;
        const bf16x8* ph = (const bf16x8*)(Qhi + ((size_t)bb*NN + mrow)*NC2);
        const bf16x8* pl = (const bf16x8*)(Qlo + ((size_t)bb*NN + mrow)*NC2);
        #pragma unroll
        for (int kk = 0; kk < 4; ++kk) { qh[kk] = ph[kk*4+gp]; ql[kk] = pl[kk*4+gp]; }
    }

    f32x4 acc[16];
    #pragma unroll
    for (int i = 0; i < 16; ++i) acc[i] = (f32x4){0.f, 0.f, 0.f, 0.f};
    float m_run[4] = {-3.0e38f, -3.0e38f, -3.0e38f, -3.0e38f};
    float l_run[4] = {0.f, 0.f, 0.f, 0.f};

    const char* kvb = KV + ((size_t)bb << 22);  // b * 64 tiles * 64 KB

    // prologue: stage tile 0
    {
        const char* src = kvb;
        #pragma unroll
        for (int i = 0; i < 16; ++i)
            gload16(src + ((i*256 + t) << 4), tile + ((i*256 + wv*64) << 4));
    }

    #pragma unroll 1
    for (int it = 0; it < 64; ++it) {
        asm volatile("s_waitcnt vmcnt(0)" ::: "memory");
        __syncthreads();   // all waves' LDS writes complete & visible

        // --- energy: E[m][n] over this wave's 16 rows x 64 keys ---
        f32x4 e[4];
        #pragma unroll
        for (int s = 0; s < 4; ++s) {
            f32x4 ac = {0.f, 0.f, 0.f, 0.f};
            const int n  = s*16 + cl;
            const int rb = n*256;
            const int sw = (n&7) << 4;
            #pragma unroll
            for (int kk = 0; kk < 4; ++kk) {
                const int ob = (kk*64 + gp*16) ^ sw;
                bf16x8 kh = *(const bf16x8*)(tile + rb + ob);
                bf16x8 kl = *(const bf16x8*)(tile + 16384 + rb + ob);
                ac = __builtin_amdgcn_mfma_f32_16x16x32_bf16(qh[kk], kh, ac, 0, 0, 0);
                ac = __builtin_amdgcn_mfma_f32_16x16x32_bf16(ql[kk], kh, ac, 0, 0, 0);
                ac = __builtin_amdgcn_mfma_f32_16x16x32_bf16(qh[kk], kl, ac, 0, 0, 0);
            }
            e[s] = ac;
        }

        // --- online softmax; row r lives at (gp*4 + r), spread over 16 lanes ---
        float sc[4];
        #pragma unroll
        for (int r = 0; r < 4; ++r) {
            float mx = fmaxf(fmaxf(e[0][r], e[1][r]), fmaxf(e[2][r], e[3][r]));
            #pragma unroll
            for (int mk = 1; mk <= 8; mk <<= 1) mx = fmaxf(mx, __shfl_xor(mx, mk));
            const float mn = fmaxf(m_run[r], mx);
            const float s_ = __expf(m_run[r] - mn);
            m_run[r] = mn; sc[r] = s_;
            float rs = 0.f;
            #pragma unroll
            for (int s2 = 0; s2 < 4; ++s2) {
                const float p = __expf(e[s2][r] - mn);
                e[s2][r] = p;
                rs += p;
            }
            #pragma unroll
            for (int mk = 1; mk <= 8; mk <<= 1) rs += __shfl_xor(rs, mk);
            l_run[r] = l_run[r]*s_ + rs;
        }
        #pragma unroll
        for (int tt = 0; tt < 16; ++tt) {
            acc[tt][0] *= sc[0]; acc[tt][1] *= sc[1];
            acc[tt][2] *= sc[2]; acc[tt][3] *= sc[3];
        }

        // --- P -> LDS (bf16, swizzled), per-wave private region ---
        char* pb = (char*)pld + wv*2048;
        #pragma unroll
        for (int s2 = 0; s2 < 4; ++s2) {
            #pragma unroll
            for (int r = 0; r < 4; ++r) {
                const int row = gp*4 + r;
                const int nb  = (s2*16 + cl) * 2;
                *(short*)(pb + row*128 + (nb ^ ((row&7)<<4))) = (short)f2bf(e[s2][r]);
            }
        }

        // --- PV: acc[m][o] += P[m][n] * V[o][n] ---
        #pragma unroll
        for (int ks = 0; ks < 2; ++ks) {
            const int ob = ks*64 + gp*16;
            bf16x8 pa = *(const bf16x8*)(pb + cl*128 + (ob ^ ((cl&7)<<4)));
            #pragma unroll
            for (int tt = 0; tt < 16; ++tt) {
                const int o = tt*16 + cl;
                bf16x8 vf = *(const bf16x8*)(tile + 32768 + o*128 + (ob ^ ((o&7)<<4)));
                acc[tt] = __builtin_amdgcn_mfma_f32_16x16x32_bf16(pa, vf, acc[tt], 0, 0, 0);
            }
        }

        __syncthreads();   // all waves done reading this tile
        if (it < 63) {
            const char* src = kvb + ((size_t)(it+1) << 16);
            #pragma unroll
            for (int i = 0; i < 16; ++i)
                gload16(src + ((i*256 + t) << 4), tile + ((i*256 + wv*64) << 4));
        }
    }

    // --- epilogue: out = gamma * acc/l + y ---
    float inv[4];
    #pragma unroll
    for (int r = 0; r < 4; ++r) inv[r] = 1.0f / l_run[r];
    const float ga = gamma[0];
    const int mbase = m0 + wv*16 + gp*4;
    #pragma unroll
    for (int tt = 0; tt < 16; ++tt) {
        const int o = tt*16 + cl;
        const size_t base = ((size_t)(bb*NC + o))*NN + mbase;
        f32x4 yv = *(const f32x4*)(yg + base);
        f32x4 ov;
        ov[0] = fmaf(acc[tt][0]*inv[0], ga, yv[0]);
        ov[1] = fmaf(acc[tt][1]*inv[1], ga, yv[1]);
        ov[2] = fmaf(acc[tt][2]*inv[2], ga, yv[2]);
        ov[3] = fmaf(acc[tt][3]*inv[3], ga, yv[3]);
        *(f32x4*)(outp + base) = ov;
    }
}

extern "C" void kernel_launch(void* const* d_in, const int* in_sizes, int n_in,
                              void* d_out, int out_size, void* d_ws, size_t ws_size,
                              hipStream_t stream) {
    (void)in_sizes; (void)n_in; (void)out_size; (void)ws_size;
    const float* x     = (const float*)d_in[0];
    const float* y     = (const float*)d_in[1];
    const float* Wq    = (const float*)d_in[2];
    const float* bq    = (const float*)d_in[3];
    const float* Wk    = (const float*)d_in[4];
    const float* bk    = (const float*)d_in[5];
    const float* Wv    = (const float*)d_in[6];
    const float* bv    = (const float*)d_in[7];
    const float* gamma = (const float*)d_in[8];
    float* out = (float*)d_out;

    unsigned short* Qhi = (unsigned short*)d_ws;
    unsigned short* Qlo = Qhi + (size_t)NB*NN*NC2;
    char* KV = (char*)(Qlo + (size_t)NB*NN*NC2);   // 16 b x 64 tiles x 64 KB

    qkv_kernel<<<dim3(4096), dim3(256), 0, stream>>>(
        x, y, Wq, bq, Wk, bk, Wv, bv, Qhi, Qlo, KV);
    attn_kernel<<<dim3(1024), dim3(256), 0, stream>>>(
        Qhi, Qlo, KV, y, gamma, out);
}

// Round 4
// 456.344 us; speedup vs baseline: 4.3466x; 1.5791x over previous
//
#include <hip/hip_runtime.h>
#include <stdint.h>

using f32x4  = __attribute__((ext_vector_type(4))) float;
using f32x16 = __attribute__((ext_vector_type(16))) float;
using f16x8  = __attribute__((ext_vector_type(8))) _Float16;

#define NB  16
#define NC  256
#define NC2 128
#define NN  4096
#define TILE_B 49152   // 48 KB per 64-key tile: K 16K (64x256B swz) + V 32K (256x128B swz)

__device__ __forceinline__ unsigned int pk2(float a, float b) {
    auto h = __builtin_amdgcn_cvt_pkrtz(a, b);   // __fp16 ext_vector(2)
    return __builtin_bit_cast(unsigned int, h);
}

__device__ __forceinline__ void gload16(const void* g, void* l) {
    __builtin_amdgcn_global_load_lds(
        (const __attribute__((address_space(1))) unsigned int*)g,
        (__attribute__((address_space(3))) unsigned int*)l, 16, 0, 0);
}

// ---------------------------------------------------------------------------
// Phase 1: 1x1-conv projections (f32 SGEMM), outputs in f16.
//  - Q -> linear [b][n][128] f16.
//  - K,V -> tile-major PRE-SWIZZLED workspace: per (b, 64-key tile) one 48 KB
//    block [K 16K | V 32K] laid out exactly as attn's LDS image (XOR-16B bank
//    swizzle applied), so attn stages it with linear global_load_lds.
// Grid: 16 b x 64 ntiles x 4 units (Q, K, V-lo, V-hi) = 4096 blocks.
// ---------------------------------------------------------------------------
__global__ __launch_bounds__(256, 4) void qkv_kernel(
    const float* __restrict__ x, const float* __restrict__ y,
    const float* __restrict__ Wq, const float* __restrict__ bq,
    const float* __restrict__ Wk, const float* __restrict__ bk,
    const float* __restrict__ Wv, const float* __restrict__ bv,
    unsigned short* __restrict__ Qf, char* __restrict__ KV)
{
    __shared__ float Sld[8][64];    // src tile: 8 channels x 64 positions
    __shared__ float Wld[8][128];   // weight tile: 8 channels x 128 outputs

    const int bid   = blockIdx.x;
    const int unit  = bid & 3;
    const int ntile = (bid >> 2) & 63;
    const int bb    = bid >> 8;
    const int n0    = ntile * 64;

    const float* src  = (unit == 0) ? x : y;
    const float* W    = (unit == 0) ? Wq : ((unit == 1) ? Wk : Wv);
    const float* bias = (unit == 0) ? bq : ((unit == 1) ? bk : bv);
    const int o0 = (unit == 3) ? 128 : 0;

    const int t  = threadIdx.x;
    const int tn = t & 15;   // 4 positions each
    const int to = t >> 4;   // 8 outputs each

    float acc[4][8];
    #pragma unroll
    for (int i = 0; i < 4; ++i)
        #pragma unroll
        for (int j = 0; j < 8; ++j) acc[i][j] = 0.f;

    float bs[8];
    #pragma unroll
    for (int j = 0; j < 8; ++j) bs[j] = bias[o0 + to*8 + j];

    #pragma unroll 1
    for (int step = 0; step < 32; ++step) {
        const int c0 = step * 8;
        f32x4 sv;
        if (t < 128)
            sv = *(const f32x4*)(src + ((size_t)(bb*NC + c0 + (t>>4)))*NN + n0 + (t&15)*4);
        f32x4 wv4 = *(const f32x4*)(W + (size_t)(o0 + (t>>1))*NC + c0 + (t&1)*4);
        __syncthreads();
        if (t < 128)
            *(f32x4*)&Sld[t>>4][(t&15)*4] = sv;
        {
            const int r = t >> 1, cc = (t & 1) * 4;
            Wld[cc+0][r] = wv4[0]; Wld[cc+1][r] = wv4[1];
            Wld[cc+2][r] = wv4[2]; Wld[cc+3][r] = wv4[3];
        }
        __syncthreads();
        #pragma unroll
        for (int c = 0; c < 8; ++c) {
            f32x4 av = *(const f32x4*)&Sld[c][tn*4];
            f32x4 b0 = *(const f32x4*)&Wld[c][to*8];
            f32x4 b1 = *(const f32x4*)&Wld[c][to*8+4];
            #pragma unroll
            for (int i = 0; i < 4; ++i) {
                const float a = av[i];
                acc[i][0] = fmaf(a, b0[0], acc[i][0]);
                acc[i][1] = fmaf(a, b0[1], acc[i][1]);
                acc[i][2] = fmaf(a, b0[2], acc[i][2]);
                acc[i][3] = fmaf(a, b0[3], acc[i][3]);
                acc[i][4] = fmaf(a, b1[0], acc[i][4]);
                acc[i][5] = fmaf(a, b1[1], acc[i][5]);
                acc[i][6] = fmaf(a, b1[2], acc[i][6]);
                acc[i][7] = fmaf(a, b1[3], acc[i][7]);
            }
        }
    }

    if (unit == 0) {
        // Q: linear f16 [b][n][128]
        #pragma unroll
        for (int i = 0; i < 4; ++i) {
            const int n = n0 + tn*4 + i;
            union { _Float16 h[8]; uint4 u4; } pk;
            #pragma unroll
            for (int j = 0; j < 8; ++j) pk.h[j] = (_Float16)(acc[i][j] + bs[j]);
            *(uint4*)(Qf + ((size_t)bb*NN + n)*NC2 + to*8) = pk.u4;
        }
    } else if (unit == 1) {
        // K: pre-swizzled LDS image, rows n (256B), 16B-granule XOR
        char* kvt = KV + (size_t)(bb*64 + ntile) * TILE_B;
        #pragma unroll
        for (int i = 0; i < 4; ++i) {
            const int nr = tn*4 + i;
            union { _Float16 h[8]; uint4 u4; } pk;
            #pragma unroll
            for (int j = 0; j < 8; ++j) pk.h[j] = (_Float16)(acc[i][j] + bs[j]);
            const int dst = nr*256 + ((to*16) ^ ((nr&7)<<4));
            *(uint4*)(kvt + dst) = pk.u4;
        }
    } else {
        // V: pre-swizzled LDS image at +16K, rows o (128B), 16B-granule XOR
        char* kvt = KV + (size_t)(bb*64 + ntile) * TILE_B + 16384;
        #pragma unroll
        for (int j = 0; j < 8; ++j) {
            const int o = o0 + to*8 + j;
            union { _Float16 h[4]; uint2 u2; } pk;
            #pragma unroll
            for (int i = 0; i < 4; ++i) pk.h[i] = (_Float16)(acc[i][j] + bs[j]);
            const int dst = o*128 + ((tn*8) ^ ((o&7)<<4));
            *(uint2*)(kvt + dst) = pk.u2;
        }
    }
}

// ---------------------------------------------------------------------------
// Phase 2: flash attention, 32x32x16 f16 MFMA, swapped operands both ways:
//   S[key][q] = K·Q   (lane owns q-column -> in-register softmax over keys)
//   O[o][q]   = V·P^T (P repacked in-register via cvt_pkrtz + shfl_xor(32))
// Block: 256 threads = 4 waves x 32 q-rows (BM=128). BN=64 keys/iter.
// K/V staged with global_load_lds (producer pre-swizzled). Defer-max (THR=8).
// ---------------------------------------------------------------------------
__global__ __launch_bounds__(256, 2) void attn_kernel(
    const unsigned short* __restrict__ Qf, const char* __restrict__ KV,
    const float* __restrict__ yg, const float* __restrict__ gamma,
    float* __restrict__ outp)
{
    __shared__ __align__(16) char tile[TILE_B];

    // T1: bijective XCD swizzle (512 blocks = 8 x 64)
    const int bid = ((blockIdx.x & 7) << 6) + (blockIdx.x >> 3);
    const int bb = bid >> 5;
    const int m0 = (bid & 31) * 128;
    const int t    = threadIdx.x;
    const int lane = t & 63;
    const int wv   = t >> 6;
    const int qcol = lane & 31;   // this lane's q column (within wave's 32 rows)
    const int s    = lane >> 5;   // half-wave index

    // Q B-frags: element j <-> c = ks*16 + s*8 + j
    f16x8 qf[8];
    {
        const char* qrow = (const char*)Qf +
            (((size_t)bb*NN + m0 + wv*32 + qcol) * NC2) * 2;
        #pragma unroll
        for (int ks = 0; ks < 8; ++ks)
            qf[ks] = *(const f16x8*)(qrow + ks*32 + s*16);
    }

    f32x16 acc[8];
    #pragma unroll
    for (int ob = 0; ob < 8; ++ob) acc[ob] = (f32x16)(0.0f);
    float m_run = -3.0e38f, l_run = 0.0f;

    const char* kvb = KV + (size_t)bb * 64 * TILE_B;

    // prologue: stage tile 0 (12 x 16B per thread = 48 KB)
    #pragma unroll
    for (int i = 0; i < 12; ++i)
        gload16(kvb + ((i*256 + t) << 4), tile + ((i*256 + wv*64) << 4));

    #pragma unroll 1
    for (int it = 0; it < 64; ++it) {
        asm volatile("s_waitcnt vmcnt(0)" ::: "memory");
        __syncthreads();   // all waves' LDS writes complete & visible

        #pragma unroll
        for (int kb = 0; kb < 2; ++kb) {
            // --- S = K·Q over 32 keys x 32 q ---
            f32x16 sS = (f32x16)(0.0f);
            const int key = kb*32 + qcol;
            const int rb  = key*256;
            const int sw  = (key&7) << 4;
            #pragma unroll
            for (int ks = 0; ks < 8; ++ks) {
                f16x8 kf = *(const f16x8*)(tile + rb + ((ks*32 + s*16) ^ sw));
                sS = __builtin_amdgcn_mfma_f32_32x32x16_f16(kf, qf[ks], sS, 0, 0, 0);
            }

            // --- online softmax over keys (in-register; lane holds 16 keys) ---
            float pmax = fmaxf(fmaxf(fmaxf(sS[0], sS[1]), fmaxf(sS[2], sS[3])),
                               fmaxf(fmaxf(sS[4], sS[5]), fmaxf(sS[6], sS[7])));
            pmax = fmaxf(pmax,
                   fmaxf(fmaxf(fmaxf(sS[8], sS[9]), fmaxf(sS[10], sS[11])),
                         fmaxf(fmaxf(sS[12], sS[13]), fmaxf(sS[14], sS[15]))));
            pmax = fmaxf(pmax, __shfl_xor(pmax, 32));
            if (__any(pmax > m_run + 8.0f)) {       // T13 defer-max
                const float mn = fmaxf(m_run, pmax);
                const float sc = __expf(m_run - mn);
                m_run = mn; l_run *= sc;
                #pragma unroll
                for (int ob = 0; ob < 8; ++ob)
                    #pragma unroll
                    for (int r = 0; r < 16; ++r) acc[ob][r] *= sc;
            }
            float p[16];
            float rs = 0.f;
            #pragma unroll
            for (int r = 0; r < 16; ++r) {
                p[r] = __expf(sS[r] - m_run);
                rs += p[r];
            }
            rs += __shfl_xor(rs, 32);
            l_run += rs;

            // --- pack P -> f16 B-frags (element j <-> key kb*32+ks2*16+s*8+j) ---
            f16x8 pb0, pb1;
            #pragma unroll
            for (int ks2 = 0; ks2 < 2; ++ks2) {
                unsigned int pA0, pA1, pB0, pB1;
                if (ks2 == 0) {
                    pA0 = pk2(p[0], p[1]);  pA1 = pk2(p[2], p[3]);
                    pB0 = pk2(p[4], p[5]);  pB1 = pk2(p[6], p[7]);
                } else {
                    pA0 = pk2(p[8], p[9]);  pA1 = pk2(p[10], p[11]);
                    pB0 = pk2(p[12], p[13]); pB1 = pk2(p[14], p[15]);
                }
                const unsigned int lv0 = s ? pB0 : pA0;
                const unsigned int lv1 = s ? pB1 : pA1;
                const unsigned int sd0 = s ? pA0 : pB0;
                const unsigned int sd1 = s ? pA1 : pB1;
                const unsigned int rv0 = (unsigned int)__shfl_xor((int)sd0, 32);
                const unsigned int rv1 = (unsigned int)__shfl_xor((int)sd1, 32);
                union { unsigned int w[4]; f16x8 v; } u;
                u.w[0] = s ? rv0 : lv0;
                u.w[1] = s ? rv1 : lv1;
                u.w[2] = s ? lv0 : rv0;
                u.w[3] = s ? lv1 : rv1;
                if (ks2 == 0) pb0 = u.v; else pb1 = u.v;
            }

            // --- O += V·P^T : 16 MFMA, V A-frags from LDS ---
            #pragma unroll
            for (int ks2 = 0; ks2 < 2; ++ks2) {
                const int colb = kb*64 + ks2*32 + s*16;
                const f16x8 pbx = ks2 ? pb1 : pb0;
                #pragma unroll
                for (int ob = 0; ob < 8; ++ob) {
                    const int o = ob*32 + qcol;
                    f16x8 vf = *(const f16x8*)(tile + 16384 + o*128 +
                                               (colb ^ ((o&7)<<4)));
                    acc[ob] = __builtin_amdgcn_mfma_f32_32x32x16_f16(vf, pbx, acc[ob], 0, 0, 0);
                }
            }
        }

        __syncthreads();   // all waves done reading this tile
        if (it < 63) {
            const char* src = kvb + (size_t)(it+1) * TILE_B;
            #pragma unroll
            for (int i = 0; i < 12; ++i)
                gload16(src + ((i*256 + t) << 4), tile + ((i*256 + wv*64) << 4));
        }
    }

    // --- epilogue: out[o][n] = gamma * acc/l + y ---
    const float ga   = gamma[0];
    const float invl = 1.0f / l_run;
    const int n = m0 + wv*32 + qcol;
    #pragma unroll
    for (int ob = 0; ob < 8; ++ob) {
        #pragma unroll
        for (int r = 0; r < 16; ++r) {
            const int o = ob*32 + (r&3) + 8*(r>>2) + 4*s;
            const size_t a = ((size_t)(bb*NC + o))*NN + n;
            outp[a] = fmaf(acc[ob][r]*invl, ga, yg[a]);
        }
    }
}

extern "C" void kernel_launch(void* const* d_in, const int* in_sizes, int n_in,
                              void* d_out, int out_size, void* d_ws, size_t ws_size,
                              hipStream_t stream) {
    (void)in_sizes; (void)n_in; (void)out_size; (void)ws_size;
    const float* x     = (const float*)d_in[0];
    const float* y     = (const float*)d_in[1];
    const float* Wq    = (const float*)d_in[2];
    const float* bq    = (const float*)d_in[3];
    const float* Wk    = (const float*)d_in[4];
    const float* bk    = (const float*)d_in[5];
    const float* Wv    = (const float*)d_in[6];
    const float* bv    = (const float*)d_in[7];
    const float* gamma = (const float*)d_in[8];
    float* out = (float*)d_out;

    unsigned short* Qf = (unsigned short*)d_ws;              // 16 MB f16
    char* KV = (char*)(Qf + (size_t)NB*NN*NC2);              // 48 MB tiles

    qkv_kernel<<<dim3(4096), dim3(256), 0, stream>>>(
        x, y, Wq, bq, Wk, bk, Wv, bv, Qf, KV);
    attn_kernel<<<dim3(512), dim3(256), 0, stream>>>(
        Qf, KV, y, gamma, out);
}